// Round 6
// baseline (3253.162 us; speedup 1.0000x reference)
//
#include <hip/hip_runtime.h>
#include <hip/hip_bf16.h>
#include <stddef.h>
#include <stdint.h>

#define T_STEPS 512
#define B_SZ 256
#define H_SZ 256
#define G4H 1024  // 4*H
#define HS_PAR 4096   // shorts per h parity buffer (A-fragment order: 8 ks x 512)

typedef __attribute__((ext_vector_type(8))) short bf16x8;
typedef __attribute__((ext_vector_type(4))) float f32x4;

__device__ __forceinline__ unsigned short f2bf(float f) {
  union { float f; unsigned u; } v; v.f = f;
  unsigned r = v.u + 0x7fffu + ((v.u >> 16) & 1u);
  return (unsigned short)(r >> 16);
}
__device__ __forceinline__ float bf2f(unsigned short h) {
  union { unsigned u; float f; } v; v.u = ((unsigned)h) << 16; return v.f;
}
__device__ __forceinline__ float sigmoid_f(float x) {
  return 1.0f / (1.0f + __expf(-x));
}
__device__ __forceinline__ float tanh_f(float x) {
  return 1.0f - 2.0f / (__expf(2.0f * x) + 1.0f);
}

// ---------------- prep: fp32->bf16 weights, bias sum, state init ----------------
__global__ void prep_kernel(const float* __restrict__ h0, const float* __restrict__ c0,
                            const float* __restrict__ W_ih, const float* __restrict__ W_hh,
                            const float* __restrict__ b_ih, const float* __restrict__ b_hh,
                            unsigned short* __restrict__ Wih_bf, unsigned short* __restrict__ Whh_bf,
                            float* __restrict__ bias, unsigned short* __restrict__ h_st,
                            float* __restrict__ c_st) {
  int i = blockIdx.x * 256 + threadIdx.x;
  int stride = gridDim.x * 256;
  for (int k = i; k < G4H * H_SZ; k += stride) {
    Wih_bf[k] = f2bf(W_ih[k]);
    Whh_bf[k] = f2bf(W_hh[k]);
  }
  for (int k = i; k < B_SZ * H_SZ; k += stride) {
    h_st[k] = f2bf(h0[k]);
    c_st[k] = c0[k];
  }
  for (int k = i; k < G4H; k += stride) bias[k] = b_ih[k] + b_hh[k];
}

// ---------------- K1: xg = bf16( embed[idx] @ W_ih^T + b_ih + b_hh )
// Swizzled for K2: value (t_loc, b, n), n = g*256 + j ->
//   flat = (((t_loc*16 + bg)*1024) + tid2)*16 + g*4 + r
//   where bg=b>>4, m=b&15, quad=m>>2, r=m&3, tid2 = (j>>4)*64 + quad*16 + (j&15).
__global__ __launch_bounds__(256, 2) void xgate_kernel(
    const int* __restrict__ enc, const float* __restrict__ embed,
    const unsigned short* __restrict__ Wih_bf, const float* __restrict__ bias,
    unsigned short* __restrict__ xg, int t0, int Ci) {
  __shared__ __align__(16) unsigned short As[64][264];
  const int tid = threadIdx.x;
  const int mbase = blockIdx.x * 64;

  // stage A tile: 64 rows of embed (gather), fp32 -> bf16
  {
    int r = tid >> 2, q = tid & 3;
    int mg = mbase + r;
    int s = mg >> 8, b = mg & 255;
    int vid = enc[(t0 + s) * B_SZ + b];
    const float4* src = (const float4*)(embed + (size_t)vid * H_SZ) + q * 16;
#pragma unroll
    for (int j = 0; j < 16; ++j) {
      float4 x = src[j];
      ushort4 o;
      o.x = f2bf(x.x); o.y = f2bf(x.y); o.z = f2bf(x.z); o.w = f2bf(x.w);
      *(ushort4*)&As[r][q * 64 + j * 4] = o;
    }
  }
  __syncthreads();

  const int wave = tid >> 6, lane = tid & 63;
  const int lrow = lane & 15, quad = lane >> 4;
  const int g = blockIdx.y;  // gate index

  // A fragments fully resident: 4 m-tiles x 8 k-steps
  bf16x8 af[4][8];
#pragma unroll
  for (int mt = 0; mt < 4; ++mt)
#pragma unroll
    for (int ks = 0; ks < 8; ++ks)
      af[mt][ks] = *(const bf16x8*)&As[mt * 16 + lrow][ks * 32 + quad * 8];

  const int t_loc = mbase >> 8;

#pragma unroll
  for (int nt = 0; nt < 4; ++nt) {
    const int j = wave * 64 + nt * 16 + lrow;      // hidden column
    const int nrow = g * 256 + j;                  // W_ih row
    const unsigned short* wrow = Wih_bf + (size_t)nrow * H_SZ + quad * 8;
    bf16x8 bf[8];
#pragma unroll
    for (int ks = 0; ks < 8; ++ks) bf[ks] = *(const bf16x8*)(wrow + ks * 32);
    const float bs = bias[nrow];
#pragma unroll
    for (int mt = 0; mt < 4; ++mt) {
      f32x4 a = {0.f, 0.f, 0.f, 0.f};
#pragma unroll
      for (int ks = 0; ks < 8; ++ks)
        a = __builtin_amdgcn_mfma_f32_16x16x32_bf16(af[mt][ks], bf[ks], a, 0, 0, 0);
      // rows m = mbase + mt*16 + quad*4 + r -> bg = (mbase>>4 & 15) + mt, same quad/r
      const int bg = ((mbase >> 4) & 15) + mt;
      const int tid2 = (wave * 4 + nt) * 64 + quad * 16 + lrow;
      const size_t off = (((size_t)t_loc * 16 + bg) * 1024 + tid2) * 16 + g * 4;
      ushort4 o;
      o.x = f2bf(a[0] + bs); o.y = f2bf(a[1] + bs);
      o.z = f2bf(a[2] + bs); o.w = f2bf(a[3] + bs);
      *(ushort4*)(xg + off) = o;
    }
  }
}

// ---------------- K2: recurrent. 16 blocks x 512 threads (8 waves, 2/SIMD).
// Block owns 16 batches; wave w owns hidden cols j = w*32 .. w*32+31 (two 16-col tiles),
// ALL 4 gates. W split: gates i,f,g register-resident (192 VGPRs incl. AGPR headroom),
// gate o in LDS (128 KB). NO per-step global W traffic — only the xg stream.
// h double-buffered in LDS in A-FRAGMENT ORDER (conflict-free b128 reads, shared by
// both j-tiles); ONE __syncthreads per step; no cross-block traffic.
__global__ __launch_bounds__(512) void lstm_kernel(
    const unsigned short* __restrict__ Whh_bf, const unsigned short* __restrict__ xg,
    unsigned short* __restrict__ h_st, float* __restrict__ c_st,
    float* __restrict__ out, int t0, int Ci) {
  __shared__ __align__(16) unsigned short Hs[2 * HS_PAR];  // 16 KB (h, frag order, dbuf)
  __shared__ __align__(16) unsigned short Wo[16 * 4096];   // 128 KB (gate-o fragments)
  // total static LDS 144 KB (gfx950: 160 KB/CU) -> 1 block/CU, 2 waves/SIMD

  const int tid = threadIdx.x, w = tid >> 6, lane = tid & 63;
  const int lrow = lane & 15, quad = lane >> 4;
  const int b0 = blockIdx.x * 16;
  const int jc0 = w * 32 + lrow;        // jt=0 column
  const int jc1 = jc0 + 16;             // jt=1 column

  // gates 0,1,2 (i,f,g) register-resident for both j-tiles: 3x2x8x4 = 192 regs
  bf16x8 wfi[2][8], wff[2][8], wfg[2][8];
#pragma unroll
  for (int jt = 0; jt < 2; ++jt) {
    const int jc = jt ? jc1 : jc0;
    const unsigned short* wr0 = Whh_bf + (size_t)(0 * 256 + jc) * H_SZ + quad * 8;
    const unsigned short* wr1 = Whh_bf + (size_t)(1 * 256 + jc) * H_SZ + quad * 8;
    const unsigned short* wr2 = Whh_bf + (size_t)(2 * 256 + jc) * H_SZ + quad * 8;
#pragma unroll
    for (int ks = 0; ks < 8; ++ks) {
      wfi[jt][ks] = *(const bf16x8*)(wr0 + ks * 32);
      wff[jt][ks] = *(const bf16x8*)(wr1 + ks * 32);
      wfg[jt][ks] = *(const bf16x8*)(wr2 + ks * 32);
    }
  }
  // gate 3 (o) staged into LDS, fragment order: tile index (w*2+jt)
  {
#pragma unroll
    for (int jt = 0; jt < 2; ++jt) {
      const int jc = jt ? jc1 : jc0;
      const unsigned short* wr3 = Whh_bf + (size_t)(3 * 256 + jc) * H_SZ + quad * 8;
#pragma unroll
      for (int ks = 0; ks < 8; ++ks) {
        bf16x8 v = *(const bf16x8*)(wr3 + ks * 32);
        *(bf16x8*)&Wo[((w * 2 + jt) * 8 + ks) * 512 + lane * 8] = v;
      }
    }
  }

  // stage h into parity-0 LDS buffer in A-fragment order:
  // frag addr(m, k) = (k>>5)*512 + (((k>>3)&3)*16 + m)*8 + (k&7)
  {
    int m = tid >> 5, kgrp = tid & 31;  // kgrp: group of 8 k's
    const unsigned short* src = h_st + (size_t)(b0 + m) * H_SZ + kgrp * 8;
    uint4 v = *(const uint4*)src;
    *(uint4*)&Hs[(kgrp >> 2) * 512 + ((kgrp & 3) * 16 + m) * 8] = v;
  }

  float creg[2][4];
#pragma unroll
  for (int jt = 0; jt < 2; ++jt)
#pragma unroll
    for (int r = 0; r < 4; ++r)
      creg[jt][r] = c_st[(size_t)(b0 + quad * 4 + r) * H_SZ + (jt ? jc1 : jc0)];

  // xg pointers: per tile, lane reads 16 contiguous shorts (2 x b128) per step
  const int tid2_0 = (w * 2 + 0) * 64 + quad * 16 + lrow;
  const int tid2_1 = (w * 2 + 1) * 64 + quad * 16 + lrow;
  const unsigned short* pxg0 = xg + ((size_t)blockIdx.x * 1024 + tid2_0) * 16;
  const unsigned short* pxg1 = xg + ((size_t)blockIdx.x * 1024 + tid2_1) * 16;
  __syncthreads();

  // h-write frag address (within parity): for (m=quad*4+r, j=jc(jt)):
  //   ks_w = w, addr = w*512 + ((jt*2 + (lrow>>3))*16 + quad*4 + r)*8 + (lrow&7)
  const int hw0 = w * 512 + ((0 * 2 + (lrow >> 3)) * 16 + quad * 4) * 8 + (lrow & 7);
  const int hw1 = w * 512 + ((1 * 2 + (lrow >> 3)) * 16 + quad * 4) * 8 + (lrow & 7);

#pragma unroll 1
  for (int s = 0; s < Ci; ++s) {
    const int rp = (s & 1) * HS_PAR;        // read parity (shorts)
    const int wp = HS_PAR - rp;             // write parity

    // A fragments: shared across j-tiles and gates; conflict-free b128 reads
    bf16x8 af[8];
#pragma unroll
    for (int ks = 0; ks < 8; ++ks)
      af[ks] = *(const bf16x8*)&Hs[rp + ks * 512 + lane * 8];

    // xg loads (independent; latency hidden under MFMA chain)
    uint4 xa00 = *(const uint4*)pxg0;
    uint4 xa01 = *(const uint4*)(pxg0 + 8);
    uint4 xa10 = *(const uint4*)pxg1;
    uint4 xa11 = *(const uint4*)(pxg1 + 8);
    pxg0 += (size_t)16 * 1024 * 16;
    pxg1 += (size_t)16 * 1024 * 16;

#pragma unroll
    for (int jt = 0; jt < 2; ++jt) {
      const unsigned short* wol = &Wo[(w * 2 + jt) * 8 * 512 + lane * 8];
      f32x4 a0 = {0.f, 0.f, 0.f, 0.f}, a1 = a0, a2 = a0, a3 = a0;
#pragma unroll
      for (int ks = 0; ks < 8; ++ks) {
        bf16x8 wo = *(const bf16x8*)(wol + ks * 512);
        a0 = __builtin_amdgcn_mfma_f32_16x16x32_bf16(af[ks], wfi[jt][ks], a0, 0, 0, 0);
        a1 = __builtin_amdgcn_mfma_f32_16x16x32_bf16(af[ks], wff[jt][ks], a1, 0, 0, 0);
        a2 = __builtin_amdgcn_mfma_f32_16x16x32_bf16(af[ks], wfg[jt][ks], a2, 0, 0, 0);
        a3 = __builtin_amdgcn_mfma_f32_16x16x32_bf16(af[ks], wo, a3, 0, 0, 0);
      }
      const unsigned short* xv0 = jt ? (const unsigned short*)&xa10 : (const unsigned short*)&xa00;
      const unsigned short* xv1 = jt ? (const unsigned short*)&xa11 : (const unsigned short*)&xa01;
      const int hw = (jt ? hw1 : hw0) + wp;
#pragma unroll
      for (int r = 0; r < 4; ++r) {
        float gi = a0[r] + bf2f(xv0[r]);
        float gf = a1[r] + bf2f(xv0[4 + r]);
        float gg = a2[r] + bf2f(xv1[r]);
        float go = a3[r] + bf2f(xv1[4 + r]);
        gi = sigmoid_f(gi);
        gf = sigmoid_f(gf);
        gg = tanh_f(gg);
        go = sigmoid_f(go);
        float c = gf * creg[jt][r] + gi * gg;
        creg[jt][r] = c;
        float h = go * tanh_f(c);
        Hs[hw + r * 8] = f2bf(h);
      }
    }
    __syncthreads();
  }

  // final h lives at parity (Ci&1); read back this lane's values
  const int fp = (Ci & 1) * HS_PAR;
#pragma unroll
  for (int jt = 0; jt < 2; ++jt) {
    const int jc = jt ? jc1 : jc0;
    const int hw = (jt ? hw1 : hw0) + fp;
#pragma unroll
    for (int r = 0; r < 4; ++r) {
      const size_t gidx = (size_t)(b0 + quad * 4 + r) * H_SZ + jc;
      unsigned short hb = Hs[hw + r * 8];
      h_st[gidx] = hb;
      c_st[gidx] = creg[jt][r];
      if (t0 + Ci == T_STEPS) {
        out[gidx] = bf2f(hb);
        out[(size_t)B_SZ * H_SZ + gidx] = creg[jt][r];
      }
    }
  }
}

extern "C" void kernel_launch(void* const* d_in, const int* in_sizes, int n_in,
                              void* d_out, int out_size, void* d_ws, size_t ws_size,
                              hipStream_t stream) {
  const int* enc = (const int*)d_in[0];
  const float* h0 = (const float*)d_in[1];
  const float* c0 = (const float*)d_in[2];
  const float* embed = (const float*)d_in[3];
  const float* W_ih = (const float*)d_in[4];
  const float* W_hh = (const float*)d_in[5];
  const float* b_ih = (const float*)d_in[6];
  const float* b_hh = (const float*)d_in[7];
  float* out = (float*)d_out;

  char* ws = (char*)d_ws;
  unsigned short* Wih_bf = (unsigned short*)(ws);                  // 512 KB
  unsigned short* Whh_bf = (unsigned short*)(ws + (512 << 10));    // 512 KB
  float* bias = (float*)(ws + (1024 << 10));                       // 4 KB
  unsigned short* h_st = (unsigned short*)(ws + (1028 << 10));     // 128 KB
  float* c_st = (float*)(ws + (1156 << 10));                       // 256 KB
  const size_t fixed = (size_t)(1412) << 10;
  unsigned short* xg = (unsigned short*)(ws + fixed);

  const size_t per_step = (size_t)B_SZ * G4H * 2;  // 512 KB per timestep (bf16)
  int C = 1;
  if (ws_size > fixed + per_step) {
    size_t c = (ws_size - fixed) / per_step;
    C = (c > T_STEPS) ? T_STEPS : (int)c;
  }

  prep_kernel<<<dim3(256), dim3(256), 0, stream>>>(h0, c0, W_ih, W_hh, b_ih, b_hh,
                                                   Wih_bf, Whh_bf, bias, h_st, c_st);
  for (int t0 = 0; t0 < T_STEPS; t0 += C) {
    int Ci = (T_STEPS - t0 < C) ? (T_STEPS - t0) : C;
    xgate_kernel<<<dim3(Ci * 4, 4), dim3(256), 0, stream>>>(enc, embed, Wih_bf, bias,
                                                            xg, t0, Ci);
    lstm_kernel<<<dim3(16), dim3(512), 0, stream>>>(Whh_bf, xg, h_st, c_st,
                                                    out, t0, Ci);
  }
}

// Round 8
// 2899.252 us; speedup vs baseline: 1.1221x; 1.1221x over previous
//
#include <hip/hip_runtime.h>
#include <hip/hip_bf16.h>
#include <stddef.h>
#include <stdint.h>

#define T_STEPS 512
#define B_SZ 256
#define H_SZ 256
#define G4H 1024
#define HS_PAR 4096  // shorts per h parity buffer (A-fragment order: 8 ks x 512)

typedef __attribute__((ext_vector_type(8))) short bf16x8;
typedef __attribute__((ext_vector_type(4))) float f32x4;

__device__ __forceinline__ unsigned short f2bf(float f) {
  union { float f; unsigned u; } v; v.f = f;
  unsigned r = v.u + 0x7fffu + ((v.u >> 16) & 1u);
  return (unsigned short)(r >> 16);
}
__device__ __forceinline__ float bf_lo(unsigned u) {
  union { unsigned u; float f; } v; v.u = u << 16; return v.f;
}
__device__ __forceinline__ float bf_hi(unsigned u) {
  union { unsigned u; float f; } v; v.u = u & 0xffff0000u; return v.f;
}
__device__ __forceinline__ float sigmoid_f(float x) {
  float e = __builtin_amdgcn_exp2f(x * -1.44269504f);
  return __builtin_amdgcn_rcpf(1.0f + e);
}
__device__ __forceinline__ float tanh_f(float x) {
  float e = __builtin_amdgcn_exp2f(x * 2.88539008f);
  return 1.0f - 2.0f * __builtin_amdgcn_rcpf(e + 1.0f);
}

// ---------------- prep: fp32->bf16 weights, bias sum, state init ----------------
__global__ void prep_kernel(const float* __restrict__ h0, const float* __restrict__ c0,
                            const float* __restrict__ W_ih, const float* __restrict__ W_hh,
                            const float* __restrict__ b_ih, const float* __restrict__ b_hh,
                            unsigned short* __restrict__ Wih_bf, unsigned short* __restrict__ Whh_bf,
                            float* __restrict__ bias, unsigned short* __restrict__ h_st,
                            float* __restrict__ c_st) {
  int i = blockIdx.x * 256 + threadIdx.x;
  int stride = gridDim.x * 256;
  for (int k = i; k < G4H * H_SZ; k += stride) {
    Wih_bf[k] = f2bf(W_ih[k]);
    Whh_bf[k] = f2bf(W_hh[k]);
  }
  for (int k = i; k < B_SZ * H_SZ; k += stride) {
    h_st[k] = f2bf(h0[k]);
    c_st[k] = c0[k];
  }
  for (int k = i; k < G4H; k += stride) bias[k] = b_ih[k] + b_hh[k];
}

// ---------------- K1: xg = bf16( embed[idx] @ W_ih^T + b_ih + b_hh )
// xg layout (consumed by K2):
//   flat = (((t_loc*32 + bb)*16 + tau)*512) + (qt*16 + (j&15))*16 + g*4 + r
//   where b = batch, bb=b>>3, qt=(b>>2)&1, r=b&3, tau=j>>4.
//   (block stride = 512 shorts — NOT (block*512+pos)*16; that was R7's OOB bug)
// grid: (4, Ci*4) — blockIdx.x = gate, blockIdx.y = 64-row tile over (t_loc, b).
__global__ __launch_bounds__(256, 2) void xgate_kernel(
    const int* __restrict__ enc, const float* __restrict__ embed,
    const unsigned short* __restrict__ Wih_bf, const float* __restrict__ bias,
    unsigned short* __restrict__ xg, int t0, int Ci) {
  __shared__ __align__(16) unsigned short As[64][264];
  const int tid = threadIdx.x;
  const int g = blockIdx.x;
  const int mbase = blockIdx.y * 64;

  // stage A tile: 64 rows of embed (gather), fp32 -> bf16
  {
    int r = tid >> 2, q = tid & 3;
    int mg = mbase + r;
    int s = mg >> 8, b = mg & 255;
    int vid = enc[(t0 + s) * B_SZ + b];
    const float4* src = (const float4*)(embed + (size_t)vid * H_SZ) + q * 16;
#pragma unroll
    for (int j = 0; j < 16; ++j) {
      float4 x = src[j];
      ushort4 o;
      o.x = f2bf(x.x); o.y = f2bf(x.y); o.z = f2bf(x.z); o.w = f2bf(x.w);
      *(ushort4*)&As[r][q * 64 + j * 4] = o;
    }
  }
  __syncthreads();

  const int wave = tid >> 6, lane = tid & 63;
  const int lrow = lane & 15, quad = lane >> 4;

  bf16x8 af[4][8];
#pragma unroll
  for (int mt = 0; mt < 4; ++mt)
#pragma unroll
    for (int ks = 0; ks < 8; ++ks)
      af[mt][ks] = *(const bf16x8*)&As[mt * 16 + lrow][ks * 32 + quad * 8];

  const int t_loc = mbase >> 8;
  const int bloc = mbase & 255;

#pragma unroll
  for (int nt = 0; nt < 4; ++nt) {
    const int j = wave * 64 + nt * 16 + lrow;      // hidden column
    const int nrow = g * 256 + j;                  // W_ih row
    const unsigned short* wrow = Wih_bf + (size_t)nrow * H_SZ + quad * 8;
    bf16x8 bf[8];
#pragma unroll
    for (int ks = 0; ks < 8; ++ks) bf[ks] = *(const bf16x8*)(wrow + ks * 32);
    const float bs = bias[nrow];
    const int tau = j >> 4;
#pragma unroll
    for (int mt = 0; mt < 4; ++mt) {
      f32x4 a = {0.f, 0.f, 0.f, 0.f};
#pragma unroll
      for (int ks = 0; ks < 8; ++ks)
        a = __builtin_amdgcn_mfma_f32_16x16x32_bf16(af[mt][ks], bf[ks], a, 0, 0, 0);
      const int brow = bloc + mt * 16 + quad * 4;  // batch of r=0
      const int bb = brow >> 3;
      const int qt = (brow >> 2) & 1;
      const size_t off =
          (((size_t)t_loc * 32 + bb) * 16 + tau) * 512 +
          (size_t)(qt * 16 + lrow) * 16 + g * 4;
      ushort4 o;
      o.x = f2bf(a[0] + bs); o.y = f2bf(a[1] + bs);
      o.z = f2bf(a[2] + bs); o.w = f2bf(a[3] + bs);
      *(ushort4*)(xg + off) = o;
    }
  }
}

// ---------------- K2: recurrent. 32 blocks x 512 threads (8 waves, 2/SIMD).
// Block owns 8 batches (MFMA M=16, rows 8..15 padding; garbage confined to
// their own output rows and never consumed). Wave w owns cols w*32..w*32+31
// (2 tiles), all 4 gates. W: i,f register-resident (128 VGPR); g in LDS
// (15/16 tiles, tile 15 streamed); o streamed from L2.
// After MFMA+xg-add (C-layout, quads 0-1 hold real rows), gates are
// redistributed WITHIN the wave via per-wave LDS scratch (no barrier needed:
// per-wave DS ops are in-order). Post-redistribution each lane owns
// m = quad*2+{0,1} for both tiles -> elementwise VALU spread over all lanes.
__global__ __launch_bounds__(512) __attribute__((amdgpu_waves_per_eu(2, 2)))
void lstm_kernel(
    const unsigned short* __restrict__ Whh_bf, const unsigned short* __restrict__ xg,
    unsigned short* __restrict__ h_st, float* __restrict__ c_st,
    float* __restrict__ out, int t0, int Ci) {
  __shared__ __align__(16) unsigned short Hs[2 * HS_PAR];  // 16 KB
  __shared__ __align__(16) unsigned short Wg[15 * 4096];   // 120 KB
  __shared__ __align__(16) float Scr[8][512];              // 16 KB (per-wave 2 KB)
  // total 152 KB static LDS

  const int tid = threadIdx.x, w = tid >> 6, lane = tid & 63;
  const int lrow = lane & 15, quad = lane >> 4;
  const int bb = blockIdx.x, b0 = bb * 8;
  const int jc0 = w * 32 + lrow, jc1 = jc0 + 16;

  // gates i,f register-resident (both tiles): 128 regs
  bf16x8 wfi[2][8], wff[2][8];
#pragma unroll
  for (int jt = 0; jt < 2; ++jt) {
    const int jc = jt ? jc1 : jc0;
    const unsigned short* wr0 = Whh_bf + (size_t)(0 * 256 + jc) * H_SZ + quad * 8;
    const unsigned short* wr1 = Whh_bf + (size_t)(1 * 256 + jc) * H_SZ + quad * 8;
#pragma unroll
    for (int ks = 0; ks < 8; ++ks) {
      wfi[jt][ks] = *(const bf16x8*)(wr0 + ks * 32);
      wff[jt][ks] = *(const bf16x8*)(wr1 + ks * 32);
    }
  }
  // gate g -> LDS (tiles 0..14); tile 15 (wave 7, jt 1) streamed from L2
#pragma unroll
  for (int jt = 0; jt < 2; ++jt) {
    const int tau = w * 2 + jt;
    const int jc = jt ? jc1 : jc0;
    const unsigned short* wr2 = Whh_bf + (size_t)(2 * 256 + jc) * H_SZ + quad * 8;
    if (tau < 15) {
#pragma unroll
      for (int ks = 0; ks < 8; ++ks) {
        bf16x8 v = *(const bf16x8*)(wr2 + ks * 32);
        *(bf16x8*)&Wg[(tau * 8 + ks) * 512 + lane * 8] = v;
      }
    }
  }
  const unsigned short* wrg15 = Whh_bf + (size_t)(2 * 256 + jc1) * H_SZ + quad * 8;
  const unsigned short* wro0 = Whh_bf + (size_t)(3 * 256 + jc0) * H_SZ + quad * 8;
  const unsigned short* wro1 = Whh_bf + (size_t)(3 * 256 + jc1) * H_SZ + quad * 8;

  // stage h into parity-0 (A-fragment order); zero the padding rows
  {
    int m = tid >> 5, kg = tid & 31;
    uint4 v = {0u, 0u, 0u, 0u};
    if (m < 8) v = *(const uint4*)(h_st + (size_t)(b0 + m) * H_SZ + kg * 8);
    *(uint4*)&Hs[(kg >> 2) * 512 + ((kg & 3) * 16 + m) * 8] = v;
  }
  // zero parity-1 padding rows too (never written by the step loop)
  {
    int m = tid >> 5, kg = tid & 31;
    if (m >= 8) {
      uint4 z = {0u, 0u, 0u, 0u};
      *(uint4*)&Hs[HS_PAR + (kg >> 2) * 512 + ((kg & 3) * 16 + m) * 8] = z;
    }
  }

  float creg[2][2];
#pragma unroll
  for (int jt = 0; jt < 2; ++jt)
#pragma unroll
    for (int e = 0; e < 2; ++e)
      creg[jt][e] = c_st[(size_t)(b0 + quad * 2 + e) * H_SZ + (jt ? jc1 : jc0)];

  // xg prefetch for s=0 (quads 0,1 only)
  const size_t xg_lane = (size_t)(quad * 16 + lrow) * 16;
  uint4 xA[2][2];
  if (quad < 2) {
#pragma unroll
    for (int jt = 0; jt < 2; ++jt) {
      const unsigned short* p =
          xg + (((size_t)0 * 32 + bb) * 16 + w * 2 + jt) * 512 + xg_lane;
      xA[jt][0] = *(const uint4*)p;
      xA[jt][1] = *(const uint4*)(p + 8);
    }
  }
  __syncthreads();

  // h write address (within parity) for (m=quad*2+e, col=jc(jt)): +e*8
  const int hwb0 = w * 512 + ((0 * 2 + (lrow >> 3)) * 16 + quad * 2) * 8 + (lrow & 7);
  const int hwb1 = w * 512 + ((1 * 2 + (lrow >> 3)) * 16 + quad * 2) * 8 + (lrow & 7);

#pragma unroll 1
  for (int s = 0; s < Ci; ++s) {
    const int rp = (s & 1) * HS_PAR;
    const int wp = HS_PAR - rp;

    bf16x8 af[8];
#pragma unroll
    for (int ks = 0; ks < 8; ++ks)
      af[ks] = *(const bf16x8*)&Hs[rp + ks * 512 + lane * 8];

#pragma unroll
    for (int jt = 0; jt < 2; ++jt) {
      const unsigned short* wro = jt ? wro1 : wro0;
      const bool t15 = (w == 7) && (jt == 1);
      const int tau = w * 2 + jt;
      f32x4 acc[4];
#pragma unroll
      for (int g = 0; g < 4; ++g) acc[g] = (f32x4){0.f, 0.f, 0.f, 0.f};
#pragma unroll
      for (int ks = 0; ks < 8; ++ks) {
        bf16x8 wo = *(const bf16x8*)(wro + ks * 32);
        bf16x8 wg = t15 ? *(const bf16x8*)(wrg15 + ks * 32)
                        : *(const bf16x8*)&Wg[(tau * 8 + ks) * 512 + lane * 8];
        acc[0] = __builtin_amdgcn_mfma_f32_16x16x32_bf16(af[ks], wfi[jt][ks], acc[0], 0, 0, 0);
        acc[1] = __builtin_amdgcn_mfma_f32_16x16x32_bf16(af[ks], wff[jt][ks], acc[1], 0, 0, 0);
        acc[2] = __builtin_amdgcn_mfma_f32_16x16x32_bf16(af[ks], wg, acc[2], 0, 0, 0);
        acc[3] = __builtin_amdgcn_mfma_f32_16x16x32_bf16(af[ks], wo, acc[3], 0, 0, 0);
      }
      // xg add (C-layout) + scratch write: real rows live in quads 0,1
      if (quad < 2) {
        unsigned xu[8];
        xu[0] = xA[jt][0].x; xu[1] = xA[jt][0].y; xu[2] = xA[jt][0].z; xu[3] = xA[jt][0].w;
        xu[4] = xA[jt][1].x; xu[5] = xA[jt][1].y; xu[6] = xA[jt][1].z; xu[7] = xA[jt][1].w;
#pragma unroll
        for (int g = 0; g < 4; ++g) {
          acc[g][0] += bf_lo(xu[g * 2]);
          acc[g][1] += bf_hi(xu[g * 2]);
          acc[g][2] += bf_lo(xu[g * 2 + 1]);
          acc[g][3] += bf_hi(xu[g * 2 + 1]);
          *(f32x4*)&Scr[w][g * 128 + lrow * 8 + quad * 4] = acc[g];
        }
      }
      // redistribution read (all lanes; per-wave in-order DS, no barrier)
      float2 gI = *(const float2*)&Scr[w][0 * 128 + lrow * 8 + quad * 2];
      float2 gF = *(const float2*)&Scr[w][1 * 128 + lrow * 8 + quad * 2];
      float2 gG = *(const float2*)&Scr[w][2 * 128 + lrow * 8 + quad * 2];
      float2 gO = *(const float2*)&Scr[w][3 * 128 + lrow * 8 + quad * 2];
      const int hwb = (jt ? hwb1 : hwb0) + wp;
#pragma unroll
      for (int e = 0; e < 2; ++e) {
        float gi = sigmoid_f(e ? gI.y : gI.x);
        float gf = sigmoid_f(e ? gF.y : gF.x);
        float gg = tanh_f(e ? gG.y : gG.x);
        float go = sigmoid_f(e ? gO.y : gO.x);
        float c = gf * creg[jt][e] + gi * gg;
        creg[jt][e] = c;
        float h = go * tanh_f(c);
        Hs[hwb + e * 8] = f2bf(h);
      }
    }
    // prefetch next step's xg
    if (quad < 2 && s + 1 < Ci) {
#pragma unroll
      for (int jt = 0; jt < 2; ++jt) {
        const unsigned short* p =
            xg + (((size_t)(s + 1) * 32 + bb) * 16 + w * 2 + jt) * 512 + xg_lane;
        xA[jt][0] = *(const uint4*)p;
        xA[jt][1] = *(const uint4*)(p + 8);
      }
    }
    __syncthreads();
  }

  // epilogue: lane reads back its own h writes; persist state / output
  const int fp = (Ci & 1) * HS_PAR;
#pragma unroll
  for (int jt = 0; jt < 2; ++jt) {
    const int jc = jt ? jc1 : jc0;
    const int hwb = (jt ? hwb1 : hwb0) + fp;
#pragma unroll
    for (int e = 0; e < 2; ++e) {
      const size_t gidx = (size_t)(b0 + quad * 2 + e) * H_SZ + jc;
      unsigned short hb = Hs[hwb + e * 8];
      h_st[gidx] = hb;
      c_st[gidx] = creg[jt][e];
      if (t0 + Ci == T_STEPS) {
        out[gidx] = bf_lo((unsigned)hb);
        out[(size_t)B_SZ * H_SZ + gidx] = creg[jt][e];
      }
    }
  }
}

extern "C" void kernel_launch(void* const* d_in, const int* in_sizes, int n_in,
                              void* d_out, int out_size, void* d_ws, size_t ws_size,
                              hipStream_t stream) {
  const int* enc = (const int*)d_in[0];
  const float* h0 = (const float*)d_in[1];
  const float* c0 = (const float*)d_in[2];
  const float* embed = (const float*)d_in[3];
  const float* W_ih = (const float*)d_in[4];
  const float* W_hh = (const float*)d_in[5];
  const float* b_ih = (const float*)d_in[6];
  const float* b_hh = (const float*)d_in[7];
  float* out = (float*)d_out;

  char* ws = (char*)d_ws;
  unsigned short* Wih_bf = (unsigned short*)(ws);                  // 512 KB
  unsigned short* Whh_bf = (unsigned short*)(ws + (512 << 10));    // 512 KB
  float* bias = (float*)(ws + (1024 << 10));                       // 4 KB
  unsigned short* h_st = (unsigned short*)(ws + (1028 << 10));     // 128 KB
  float* c_st = (float*)(ws + (1156 << 10));                       // 256 KB
  const size_t fixed = (size_t)(1412) << 10;
  unsigned short* xg = (unsigned short*)(ws + fixed);

  const size_t per_step = (size_t)B_SZ * G4H * 2;  // 512 KB per timestep (bf16)
  int C = 1;
  if (ws_size > fixed + per_step) {
    size_t c = (ws_size - fixed) / per_step;
    C = (c > T_STEPS) ? T_STEPS : (int)c;
  }

  prep_kernel<<<dim3(256), dim3(256), 0, stream>>>(h0, c0, W_ih, W_hh, b_ih, b_hh,
                                                   Wih_bf, Whh_bf, bias, h_st, c_st);
  for (int t0 = 0; t0 < T_STEPS; t0 += C) {
    int Ci = (T_STEPS - t0 < C) ? (T_STEPS - t0) : C;
    xgate_kernel<<<dim3(4, Ci * 4), dim3(256), 0, stream>>>(enc, embed, Wih_bf, bias,
                                                            xg, t0, Ci);
    lstm_kernel<<<dim3(32), dim3(512), 0, stream>>>(Whh_bf, xg, h_st, c_st,
                                                    out, t0, Ci);
  }
}